// Round 9
// baseline (138.654 us; speedup 1.0000x reference)
//
#include <hip/hip_runtime.h>
#include <stdint.h>

#define DI __device__ __forceinline__

typedef __attribute__((ext_vector_type(8))) __bf16 bfrag;   // MFMA A/B operand (4 VGPRs)
typedef __attribute__((ext_vector_type(4))) __bf16 bf16x4;
typedef __attribute__((ext_vector_type(4))) float f32x4;    // MFMA C/D operand

static constexpr int Bb = 8, Ss = 1024, Dd = 768, Hh = 12, DKk = 64;
static constexpr int Mm = Bb * Ss;          // 8192 rows

typedef __attribute__((address_space(3))) void lds_void_t;
typedef const __attribute__((address_space(1))) void gvoid_t;

DI void async_load16(const void* g, void* lds) {
    __builtin_amdgcn_global_load_lds((gvoid_t*)(uintptr_t)g,
                                     (lds_void_t*)(uint32_t)(uintptr_t)lds, 16, 0, 0);
}

#if __has_builtin(__builtin_amdgcn_exp2f)
#define EXP2(x) __builtin_amdgcn_exp2f(x)
#else
extern "C" __device__ float __ocml_exp2_f32(float);
#define EXP2(x) __ocml_exp2_f32(x)
#endif

// ---- fp32 -> bf16 convert, 8 elems/thread, all 7 tensors in ONE launch ----
// blocks 0..9215: activations (3 x 3072); 9216..10367: weights (4 x 288)
__global__ __launch_bounds__(256) void cvt_k(const float* __restrict__ a0, const float* __restrict__ a1,
                                             const float* __restrict__ a2,
                                             const float* __restrict__ w0, const float* __restrict__ w1,
                                             const float* __restrict__ w2, const float* __restrict__ w3,
                                             __bf16* __restrict__ da0, __bf16* __restrict__ da1,
                                             __bf16* __restrict__ da2,
                                             __bf16* __restrict__ dw0, __bf16* __restrict__ dw1,
                                             __bf16* __restrict__ dw2, __bf16* __restrict__ dw3) {
    const int bid = (int)blockIdx.x;
    const float* s; __bf16* d; int off;
    if (bid < 9216) {
        const int ti = bid / 3072;
        off = (bid % 3072) * 2048;
        s = ti == 0 ? a0 : ti == 1 ? a1 : a2;
        d = ti == 0 ? da0 : ti == 1 ? da1 : da2;
    } else {
        const int b2 = bid - 9216;
        const int ti = b2 / 288;
        off = (b2 % 288) * 2048;
        s = ti == 0 ? w0 : ti == 1 ? w1 : ti == 2 ? w2 : w3;
        d = ti == 0 ? dw0 : ti == 1 ? dw1 : ti == 2 ? dw2 : dw3;
    }
    const int i = off + (int)threadIdx.x * 8;
    f32x4 a = *(const f32x4*)(s + i);
    f32x4 b = *(const f32x4*)(s + i + 4);
    bfrag o;
#pragma unroll
    for (int j = 0; j < 4; ++j) { o[j] = (__bf16)a[j]; o[j + 4] = (__bf16)b[j]; }
    *(bfrag*)(d + i) = o;
}

// ---- GEMM core v2: 128x128 tile, BK=32, DOUBLE-BUFFERED 2-phase K-loop.
// Per iter: ds_read frags(buf cur) -> issue global_load_lds STAGE(buf cur^1) ->
// MFMA -> one __syncthreads (its vmcnt(0) drain sits AFTER compute -> overlap).
// LDS per buffer: A 8KB + B 8KB; chunk-swizzle c ^ ((r>>1)&3) -> 2-way (free)
// on both the (implicitly linear) write and the b128 read.
DI void stage_bk32(const __bf16* __restrict__ A, const __bf16* __restrict__ W,
                   char* buf, int row0, int col0, int k0, int w, int lane) {
#pragma unroll
    for (int o = 0; o < 2; ++o) {
        const int r = o * 64 + w * 16 + (lane >> 2);   // tile row 0..127 (per-lane)
        const int cg = (lane & 3) ^ ((r >> 1) & 3);    // pre-swizzled global chunk
        async_load16(A + (size_t)(row0 + r) * Dd + k0 + cg * 8, buf + o * 4096 + w * 1024);
        async_load16(W + (size_t)(col0 + r) * Dd + k0 + cg * 8, buf + 8192 + o * 4096 + w * 1024);
    }
}

DI void gemm_core(const __bf16* __restrict__ A, const __bf16* __restrict__ W,
                  char* smem, int row0, int col0, int t, f32x4 acc[4][4]) {
    const int lane = t & 63, w = t >> 6;
    const int l15 = lane & 15, lg = lane >> 4;
    const int wr = (w >> 1) * 64, wc = (w & 1) * 64;

    // prologue: stage tile 0 into buffer 0
    stage_bk32(A, W, smem, row0, col0, 0, w, lane);
    __syncthreads();

    int cur = 0;
    for (int kt = 0; kt < 24; ++kt) {
        const __bf16* Ac = (const __bf16*)(smem + cur * 16384);
        const __bf16* Bc = (const __bf16*)(smem + cur * 16384 + 8192);

        bfrag af[4], bf[4];
#pragma unroll
        for (int mi = 0; mi < 4; ++mi) {
            const int ra = wr + mi * 16 + l15;
            const int rb = wc + mi * 16 + l15;
            af[mi] = *(const bfrag*)(Ac + ra * 32 + ((lg ^ ((ra >> 1) & 3)) * 8));
            bf[mi] = *(const bfrag*)(Bc + rb * 32 + ((lg ^ ((rb >> 1) & 3)) * 8));
        }

        if (kt < 23)
            stage_bk32(A, W, smem + (cur ^ 1) * 16384, row0, col0, (kt + 1) * 32, w, lane);

#pragma unroll
        for (int mi = 0; mi < 4; ++mi)
#pragma unroll
            for (int ni = 0; ni < 4; ++ni)
                acc[mi][ni] = __builtin_amdgcn_mfma_f32_16x16x32_bf16(af[mi], bf[ni],
                                                                      acc[mi][ni], 0, 0, 0);
        __syncthreads();   // drains vmcnt(0): next tile landed; all reads done
        cur ^= 1;
    }
}

// ---- fused QKV projection: grid (64 M-tiles, 6 N-tiles, 3 tensors) ----
// z=0: Q (scaled 0.125*log2e) -> [B,H,S,64]; z=1: K -> [B,H,S,64]; z=2: V -> V^T [B,H,64,S]
__global__ __launch_bounds__(256) void qkv_gemm(const __bf16* __restrict__ qA, const __bf16* __restrict__ kA,
                                                const __bf16* __restrict__ vA,
                                                const __bf16* __restrict__ qW, const __bf16* __restrict__ kW,
                                                const __bf16* __restrict__ vW,
                                                const float* __restrict__ qb, const float* __restrict__ kb,
                                                const float* __restrict__ vb,
                                                __bf16* __restrict__ qO, __bf16* __restrict__ kO,
                                                __bf16* __restrict__ vO) {
    __shared__ __attribute__((aligned(16))) char smem[34816];  // 32KB dbuf staging; 34816 for V-transpose
    const int z = (int)blockIdx.z;
    const __bf16* A = z == 0 ? qA : z == 1 ? kA : vA;
    const __bf16* W = z == 0 ? qW : z == 1 ? kW : vW;
    const float* bias = z == 0 ? qb : z == 1 ? kb : vb;
    __bf16* O = z == 0 ? qO : z == 1 ? kO : vO;

    const int t = (int)threadIdx.x;
    const int lane = t & 63, w = t >> 6;
    const int l15 = lane & 15, lg = lane >> 4;
    const int row0 = (int)blockIdx.x * 128, col0 = (int)blockIdx.y * 128;
    const int wr = (w >> 1) * 64, wc = (w & 1) * 64;

    f32x4 acc[4][4] = {};
    gemm_core(A, W, smem, row0, col0, t, acc);

    if (z == 2) {
        // transpose epilogue: acc -> LDS T[128 d][136 pad s] -> coalesced V^T write
        __syncthreads();
        auto T = reinterpret_cast<__bf16(*)[136]>(smem);
#pragma unroll
        for (int mi = 0; mi < 4; ++mi) {
#pragma unroll
            for (int ni = 0; ni < 4; ++ni) {
                const float bv = bias[col0 + wc + ni * 16 + l15];
#pragma unroll
                for (int j = 0; j < 4; ++j)
                    T[wc + ni * 16 + l15][wr + mi * 16 + lg * 4 + j] = (__bf16)(acc[mi][ni][j] + bv);
            }
        }
        __syncthreads();
        const int bb2 = row0 >> 10, sb = row0 & 1023;
#pragma unroll
        for (int i = 0; i < 8; ++i) {
            const int ld = i * 16 + (t >> 4);   // local d 0..127
            const int ck = (t & 15) * 8;        // s-chunk offset
            const int head = (col0 + ld) >> 6, dd = (col0 + ld) & 63;
            __bf16* dst = O + ((size_t)(bb2 * Hh + head) * DKk + dd) * Ss + sb + ck;
            *reinterpret_cast<bfrag*>(dst) = *reinterpret_cast<const bfrag*>(&T[ld][ck]);
        }
    } else {
        const float scl = (z == 0) ? 0.18033688f : 1.0f;  // 0.125 * log2(e)
#pragma unroll
        for (int mi = 0; mi < 4; ++mi) {
#pragma unroll
            for (int ni = 0; ni < 4; ++ni) {
                const int cg = col0 + wc + ni * 16 + l15;
                const float bv = bias[cg];
#pragma unroll
                for (int j = 0; j < 4; ++j) {
                    const int rg = row0 + wr + mi * 16 + lg * 4 + j;
                    const float val = (acc[mi][ni][j] + bv) * scl;
                    const int bb = rg >> 10, ss = rg & 1023;
                    const int hh2 = cg >> 6, dd = cg & 63;
                    O[((size_t)(bb * Hh + hh2) * Ss + ss) * DKk + dd] = (__bf16)val;
                }
            }
        }
    }
}

// ---- output projection: bf16 A [M][768] x bf16 Wo -> fp32 [M][768] + bias ----
__global__ __launch_bounds__(256) void o_gemm(const __bf16* __restrict__ A, const __bf16* __restrict__ W,
                                              const float* __restrict__ bias, float* __restrict__ Out) {
    __shared__ __attribute__((aligned(16))) char smem[32768];
    const int t = (int)threadIdx.x;
    const int lane = t & 63, w = t >> 6;
    const int l15 = lane & 15, lg = lane >> 4;
    const int row0 = (int)blockIdx.x * 128, col0 = (int)blockIdx.y * 128;
    const int wr = (w >> 1) * 64, wc = (w & 1) * 64;

    f32x4 acc[4][4] = {};
    gemm_core(A, W, smem, row0, col0, t, acc);

#pragma unroll
    for (int mi = 0; mi < 4; ++mi) {
#pragma unroll
        for (int ni = 0; ni < 4; ++ni) {
            const int cg = col0 + wc + ni * 16 + l15;
            const float bv = bias[cg];
#pragma unroll
            for (int j = 0; j < 4; ++j) {
                const int rg = row0 + wr + mi * 16 + lg * 4 + j;
                Out[(size_t)rg * Dd + cg] = acc[mi][ni][j] + bv;
            }
        }
    }
}

// ---- Flash attention v8 (unchanged): QBLK=64, NO-MAX base-2 softmax,
// T14 async-STAGE split + T5 setprio. 1536 blocks, 96-bijective XCD grouping. ----
__global__ __launch_bounds__(256) void attn_k(const __bf16* __restrict__ q,
                                              const __bf16* __restrict__ k,
                                              const __bf16* __restrict__ vt,
                                              __bf16* __restrict__ o) {
    __shared__ __attribute__((aligned(16))) __bf16 Ks[64][72];   // [key][d]
    __shared__ __attribute__((aligned(16))) __bf16 Vs[64][72];   // [d][key]
    __shared__ __attribute__((aligned(16))) __bf16 plds[4][16][72];
    const int t = (int)threadIdx.x;
    const int lane = t & 63, w = t >> 6;
    const int l15 = lane & 15, lg = lane >> 4;
    const int blk = (int)blockIdx.x;
    const int bh = blk % 96, qt = blk / 96;   // 96 % 8 == 0: bijective XCD grouping
    const size_t bhb = (size_t)bh * Ss;
    const __bf16* qp = q + bhb * DKk;
    const __bf16* kp = k + bhb * DKk;
    const __bf16* vtp = vt + bhb * DKk;  // V^T: [64 d][1024 s]
    const int qbase = qt * 64 + w * 16;
    const int srow = t >> 2, sc = (t & 3) * 16;  // staging: row, 16-elem chunk base

    // Q as MFMA B-operand: col = l15 = q-row, k = ks*32 + lg*8
    bfrag bq[2];
#pragma unroll
    for (int ks = 0; ks < 2; ++ks)
        bq[ks] = *reinterpret_cast<const bfrag*>(qp + (size_t)(qbase + l15) * DKk + ks * 32 + lg * 8);

    float lrow = 0.f;            // per-lane denom for q = l15 (replicated over lg)
    f32x4 oacc[4] = {};

    {   // prologue: stage tile 0
        bfrag k0a = *reinterpret_cast<const bfrag*>(kp + (size_t)srow * DKk + sc);
        bfrag k0b = *reinterpret_cast<const bfrag*>(kp + (size_t)srow * DKk + sc + 8);
        bfrag v0a = *reinterpret_cast<const bfrag*>(vtp + (size_t)srow * Ss + sc);
        bfrag v0b = *reinterpret_cast<const bfrag*>(vtp + (size_t)srow * Ss + sc + 8);
        *reinterpret_cast<bfrag*>(&Ks[srow][sc]) = k0a;
        *reinterpret_cast<bfrag*>(&Ks[srow][sc + 8]) = k0b;
        *reinterpret_cast<bfrag*>(&Vs[srow][sc]) = v0a;
        *reinterpret_cast<bfrag*>(&Vs[srow][sc + 8]) = v0b;
    }
    __syncthreads();

    for (int kt = 0; kt < 16; ++kt) {
        // T14: issue next tile's global loads BEFORE compute; write after barrier
        bfrag kna, knb, vna, vnb;
        if (kt < 15) {
            const int kb1 = (kt + 1) * 64;
            kna = *reinterpret_cast<const bfrag*>(kp + (size_t)(kb1 + srow) * DKk + sc);
            knb = *reinterpret_cast<const bfrag*>(kp + (size_t)(kb1 + srow) * DKk + sc + 8);
            vna = *reinterpret_cast<const bfrag*>(vtp + (size_t)srow * Ss + kb1 + sc);
            vnb = *reinterpret_cast<const bfrag*>(vtp + (size_t)srow * Ss + kb1 + sc + 8);
        }

        // QK^T swapped: A = K rows (key), B = Q cols (q). sacc[n][j]: key = n*16+lg*4+j, q = l15
        f32x4 sacc[4] = {};
        __builtin_amdgcn_s_setprio(1);
#pragma unroll
        for (int n = 0; n < 4; ++n) {
#pragma unroll
            for (int ks = 0; ks < 2; ++ks) {
                const bfrag ak = *reinterpret_cast<const bfrag*>(&Ks[n * 16 + l15][ks * 32 + lg * 8]);
                sacc[n] = __builtin_amdgcn_mfma_f32_16x16x32_bf16(ak, bq[ks], sacc[n], 0, 0, 0);
            }
        }
        __builtin_amdgcn_s_setprio(0);

        // no-max softmax: p = exp2(s) (Q pre-scaled by 0.125*log2e), accumulate denom
        float p[4][4];
        float rs = 0.f;
#pragma unroll
        for (int n = 0; n < 4; ++n)
#pragma unroll
            for (int j = 0; j < 4; ++j) {
                const float pe = EXP2(sacc[n][j]);
                p[n][j] = pe;
                rs += pe;
            }
        rs += __shfl_xor(rs, 16);
        rs += __shfl_xor(rs, 32);
        lrow += rs;

        // P -> wave-private LDS, packed b64: row = q = l15, keys n*16+lg*4+{0..3}
#pragma unroll
        for (int n = 0; n < 4; ++n) {
            bf16x4 pk;
#pragma unroll
            for (int j = 0; j < 4; ++j) pk[j] = (__bf16)p[n][j];
            *reinterpret_cast<bf16x4*>(&plds[w][l15][n * 16 + lg * 4]) = pk;
        }

        // PV: A = P (row = q = l15, k = key), B = V^T tile in LDS (col = d = l15)
        __builtin_amdgcn_s_setprio(1);
#pragma unroll
        for (int ks = 0; ks < 2; ++ks) {
            const bfrag ap = *reinterpret_cast<const bfrag*>(&plds[w][l15][ks * 32 + lg * 8]);
#pragma unroll
            for (int dt = 0; dt < 4; ++dt) {
                const bfrag bv = *reinterpret_cast<const bfrag*>(&Vs[dt * 16 + l15][ks * 32 + lg * 8]);
                oacc[dt] = __builtin_amdgcn_mfma_f32_16x16x32_bf16(ap, bv, oacc[dt], 0, 0, 0);
            }
        }
        __builtin_amdgcn_s_setprio(0);

        __syncthreads();  // all waves done reading Ks/Vs
        if (kt < 15) {
            *reinterpret_cast<bfrag*>(&Ks[srow][sc]) = kna;
            *reinterpret_cast<bfrag*>(&Ks[srow][sc + 8]) = knb;
            *reinterpret_cast<bfrag*>(&Vs[srow][sc]) = vna;
            *reinterpret_cast<bfrag*>(&Vs[srow][sc + 8]) = vnb;
        }
        __syncthreads();  // writes visible
    }

    // epilogue: divide by l for q = lg*4+j (held by lane lg*4+j), write [B,S,D]
    float linv[4];
#pragma unroll
    for (int j = 0; j < 4; ++j) linv[j] = 1.0f / __shfl(lrow, lg * 4 + j);
    const int bb = bh / Hh, hh = bh % Hh;
#pragma unroll
    for (int dt = 0; dt < 4; ++dt)
#pragma unroll
        for (int j = 0; j < 4; ++j) {
            const int qrow = qbase + lg * 4 + j;
            o[((size_t)(bb * Ss + qrow)) * Dd + hh * DKk + dt * 16 + l15] =
                (__bf16)(oacc[dt][j] * linv[j]);
        }
}

extern "C" void kernel_launch(void* const* d_in, const int* in_sizes, int n_in,
                              void* d_out, int out_size, void* d_ws, size_t ws_size,
                              hipStream_t stream) {
    (void)in_sizes; (void)n_in; (void)out_size; (void)ws_size;
    // dict order: key, query, value, Wk, bk, Wq, bq, Wv, bv, Wo, bo
    const float* key   = (const float*)d_in[0];
    const float* query = (const float*)d_in[1];
    const float* value = (const float*)d_in[2];
    const float* Wk = (const float*)d_in[3];
    const float* bk = (const float*)d_in[4];
    const float* Wq = (const float*)d_in[5];
    const float* bq = (const float*)d_in[6];
    const float* Wv = (const float*)d_in[7];
    const float* bvp = (const float*)d_in[8];
    const float* Wo = (const float*)d_in[9];
    const float* bo = (const float*)d_in[10];

    const size_t NA = (size_t)Mm * Dd;   // 6291456 activation elems
    const size_t NW = (size_t)Dd * Dd;   // 589824 weight elems
    __bf16* p = (__bf16*)d_ws;
    __bf16* qab = p;            p += NA;   // bf16 query
    __bf16* kab = p;            p += NA;   // bf16 key
    __bf16* vab = p;            p += NA;   // bf16 value
    __bf16* wqb = p;            p += NW;
    __bf16* wkb = p;            p += NW;
    __bf16* wvb = p;            p += NW;
    __bf16* wob = p;            p += NW;
    __bf16* qws = p;            p += NA;   // Q proj (scaled by 0.125*log2e)
    __bf16* kws = p;            p += NA;   // K proj
    __bf16* vtws = p;           p += NA;   // V^T proj
    __bf16* aws = qab;                     // attn out aliases dead qab

    dim3 blk(256);
    cvt_k<<<dim3(10368), blk, 0, stream>>>(query, key, value, Wq, Wk, Wv, Wo,
                                           qab, kab, vab, wqb, wkb, wvb, wob);
    qkv_gemm<<<dim3(Mm / 128, Dd / 128, 3), blk, 0, stream>>>(qab, kab, vab,
                                                              wqb, wkb, wvb,
                                                              bq, bk, bvp,
                                                              qws, kws, vtws);
    attn_k<<<dim3(Ss / 64 * Hh * Bb), blk, 0, stream>>>(qws, kws, vtws, aws);
    o_gemm<<<dim3(Mm / 128, Dd / 128), blk, 0, stream>>>(aws, wob, bo, (float*)d_out);
}

// Round 11
// 136.632 us; speedup vs baseline: 1.0148x; 1.0148x over previous
//
#include <hip/hip_runtime.h>
#include <stdint.h>

#define DI __device__ __forceinline__

typedef __attribute__((ext_vector_type(8))) __bf16 bfrag;   // MFMA A/B operand (4 VGPRs)
typedef __attribute__((ext_vector_type(4))) __bf16 bf16x4;
typedef __attribute__((ext_vector_type(4))) float f32x4;    // MFMA C/D operand

static constexpr int Bb = 8, Ss = 1024, Dd = 768, Hh = 12, DKk = 64;
static constexpr int Mm = Bb * Ss;          // 8192 rows

typedef __attribute__((address_space(3))) void lds_void_t;
typedef const __attribute__((address_space(1))) void gvoid_t;

DI void async_load16(const void* g, void* lds) {
    __builtin_amdgcn_global_load_lds((gvoid_t*)(uintptr_t)g,
                                     (lds_void_t*)(uint32_t)(uintptr_t)lds, 16, 0, 0);
}

#if __has_builtin(__builtin_amdgcn_exp2f)
#define EXP2(x) __builtin_amdgcn_exp2f(x)
#else
extern "C" __device__ float __ocml_exp2_f32(float);
#define EXP2(x) __ocml_exp2_f32(x)
#endif

// ---- fp32 -> bf16 convert, WEIGHTS ONLY (4 x 288 blocks, 2048 elems/block) ----
__global__ __launch_bounds__(256) void cvtw_k(const float* __restrict__ w0, const float* __restrict__ w1,
                                              const float* __restrict__ w2, const float* __restrict__ w3,
                                              __bf16* __restrict__ d0, __bf16* __restrict__ d1,
                                              __bf16* __restrict__ d2, __bf16* __restrict__ d3) {
    const int bid = (int)blockIdx.x;
    const int ti = bid / 288;
    const int i = (bid % 288) * 2048 + (int)threadIdx.x * 8;
    const float* s = ti == 0 ? w0 : ti == 1 ? w1 : ti == 2 ? w2 : w3;
    __bf16* d = ti == 0 ? d0 : ti == 1 ? d1 : ti == 2 ? d2 : d3;
    f32x4 a = *(const f32x4*)(s + i);
    f32x4 b = *(const f32x4*)(s + i + 4);
    bfrag o;
#pragma unroll
    for (int j = 0; j < 4; ++j) { o[j] = (__bf16)a[j]; o[j + 4] = (__bf16)b[j]; }
    *(bfrag*)(d + i) = o;
}

// ---- GEMM core v3: 128x128 tile, BK=32, double-buffered.
// AFP32=true: A is fp32; staged via T14 issue-early (fp32 loads at iter top) /
// write-late (cvt + swizzled ds_write after MFMA). W always bf16 global_load_lds.
// LDS layout per buffer: A 8KB + B 8KB; row r's chunk slot s holds global chunk
// s ^ ((r>>1)&3)  -> both write paths and the b128 read use the same XOR (free 2-way).
template <bool AFP32>
DI void gemm_core(const void* __restrict__ Ap, const __bf16* __restrict__ W,
                  char* smem, int row0, int col0, int t, f32x4 acc[4][4]) {
    const int lane = t & 63, w = t >> 6;
    const int l15 = lane & 15, lg = lane >> 4;
    const int wr = (w >> 1) * 64, wc = (w & 1) * 64;
    const int ar = t >> 2, ac = t & 3;   // fp32-A staging: row 0..63 (+64), chunk 0..3
    const float* Af = (const float*)Ap;
    const __bf16* Ab = (const __bf16*)Ap;

    f32x4 ra0, rb0, ra1, rb1;  // named regs (no dyn indexing)

    auto issueB = [&](int k0, char* buf) {
#pragma unroll
        for (int o = 0; o < 2; ++o) {
            const int r = o * 64 + w * 16 + (lane >> 2);
            const int cg = (lane & 3) ^ ((r >> 1) & 3);
            async_load16(W + (size_t)(col0 + r) * Dd + k0 + cg * 8, buf + 8192 + o * 4096 + w * 1024);
        }
    };
    auto issueA_lds = [&](int k0, char* buf) {
#pragma unroll
        for (int o = 0; o < 2; ++o) {
            const int r = o * 64 + w * 16 + (lane >> 2);
            const int cg = (lane & 3) ^ ((r >> 1) & 3);
            async_load16(Ab + (size_t)(row0 + r) * Dd + k0 + cg * 8, buf + o * 4096 + w * 1024);
        }
    };
    auto loadA = [&](int k0) {
        const float* s0 = Af + (size_t)(row0 + ar) * Dd + k0 + ac * 8;
        const float* s1 = Af + (size_t)(row0 + ar + 64) * Dd + k0 + ac * 8;
        ra0 = *(const f32x4*)s0; rb0 = *(const f32x4*)(s0 + 4);
        ra1 = *(const f32x4*)s1; rb1 = *(const f32x4*)(s1 + 4);
    };
    auto writeA = [&](char* buf) {
        bfrag o0, o1;
#pragma unroll
        for (int j = 0; j < 4; ++j) {
            o0[j] = (__bf16)ra0[j]; o0[j + 4] = (__bf16)rb0[j];
            o1[j] = (__bf16)ra1[j]; o1[j + 4] = (__bf16)rb1[j];
        }
        *(bfrag*)((__bf16*)buf + ar * 32 + ((ac ^ ((ar >> 1) & 3)) * 8)) = o0;
        const int r1 = ar + 64;
        *(bfrag*)((__bf16*)buf + r1 * 32 + ((ac ^ ((r1 >> 1) & 3)) * 8)) = o1;
    };

    // prologue: stage tile 0 into buffer 0
    if (AFP32) { loadA(0); writeA(smem); } else { issueA_lds(0, smem); }
    issueB(0, smem);
    __syncthreads();

    int cur = 0;
    for (int kt = 0; kt < 24; ++kt) {
        char* bufc = smem + cur * 16384;
        char* bufn = smem + (cur ^ 1) * 16384;

        if (AFP32 && kt < 23) loadA((kt + 1) * 32);   // issue early: latency under MFMA

        const __bf16* Ac = (const __bf16*)bufc;
        const __bf16* Bc = (const __bf16*)(bufc + 8192);
        bfrag af[4], bf[4];
#pragma unroll
        for (int mi = 0; mi < 4; ++mi) {
            const int rax = wr + mi * 16 + l15;
            const int rbx = wc + mi * 16 + l15;
            af[mi] = *(const bfrag*)(Ac + rax * 32 + ((lg ^ ((rax >> 1) & 3)) * 8));
            bf[mi] = *(const bfrag*)(Bc + rbx * 32 + ((lg ^ ((rbx >> 1) & 3)) * 8));
        }

        if (kt < 23) {
            issueB((kt + 1) * 32, bufn);
            if (!AFP32) issueA_lds((kt + 1) * 32, bufn);
        }

#pragma unroll
        for (int mi = 0; mi < 4; ++mi)
#pragma unroll
            for (int ni = 0; ni < 4; ++ni)
                acc[mi][ni] = __builtin_amdgcn_mfma_f32_16x16x32_bf16(af[mi], bf[ni],
                                                                      acc[mi][ni], 0, 0, 0);

        if (AFP32 && kt < 23) writeA(bufn);   // write late: vmcnt mostly drained by now

        __syncthreads();   // tile kt+1 visible; all reads of bufc done
        cur ^= 1;
    }
}

// ---- fused QKV projection from fp32 activations: grid (64, 6, 3) ----
// z=0: Q (scaled 0.125*log2e) -> [B,H,S,64]; z=1: K -> [B,H,S,64]; z=2: V -> V^T [B,H,64,S]
__global__ __launch_bounds__(256) void qkv_gemm(const float* __restrict__ qA, const float* __restrict__ kA,
                                                const float* __restrict__ vA,
                                                const __bf16* __restrict__ qW, const __bf16* __restrict__ kW,
                                                const __bf16* __restrict__ vW,
                                                const float* __restrict__ qb, const float* __restrict__ kb,
                                                const float* __restrict__ vb,
                                                __bf16* __restrict__ qO, __bf16* __restrict__ kO,
                                                __bf16* __restrict__ vO) {
    __shared__ __attribute__((aligned(16))) char smem[34816];  // 32KB dbuf; 34816 for V-transpose
    const int z = (int)blockIdx.z;
    const float* A = z == 0 ? qA : z == 1 ? kA : vA;
    const __bf16* W = z == 0 ? qW : z == 1 ? kW : vW;
    const float* bias = z == 0 ? qb : z == 1 ? kb : vb;
    __bf16* O = z == 0 ? qO : z == 1 ? kO : vO;

    const int t = (int)threadIdx.x;
    const int lane = t & 63, w = t >> 6;
    const int l15 = lane & 15, lg = lane >> 4;
    const int row0 = (int)blockIdx.x * 128, col0 = (int)blockIdx.y * 128;
    const int wr = (w >> 1) * 64, wc = (w & 1) * 64;

    f32x4 acc[4][4] = {};
    gemm_core<true>((const void*)A, W, smem, row0, col0, t, acc);

    if (z == 2) {
        // transpose epilogue: acc -> LDS T[128 d][136 pad s] -> coalesced V^T write
        __syncthreads();
        auto T = reinterpret_cast<__bf16(*)[136]>(smem);
#pragma unroll
        for (int mi = 0; mi < 4; ++mi) {
#pragma unroll
            for (int ni = 0; ni < 4; ++ni) {
                const float bv = bias[col0 + wc + ni * 16 + l15];
#pragma unroll
                for (int j = 0; j < 4; ++j)
                    T[wc + ni * 16 + l15][wr + mi * 16 + lg * 4 + j] = (__bf16)(acc[mi][ni][j] + bv);
            }
        }
        __syncthreads();
        const int bb2 = row0 >> 10, sb = row0 & 1023;
#pragma unroll
        for (int i = 0; i < 8; ++i) {
            const int ld = i * 16 + (t >> 4);   // local d 0..127
            const int ck = (t & 15) * 8;        // s-chunk offset
            const int head = (col0 + ld) >> 6, dd = (col0 + ld) & 63;
            __bf16* dst = O + ((size_t)(bb2 * Hh + head) * DKk + dd) * Ss + sb + ck;
            *reinterpret_cast<bfrag*>(dst) = *reinterpret_cast<const bfrag*>(&T[ld][ck]);
        }
    } else {
        const float scl = (z == 0) ? 0.18033688f : 1.0f;  // 0.125 * log2(e)
#pragma unroll
        for (int mi = 0; mi < 4; ++mi) {
#pragma unroll
            for (int ni = 0; ni < 4; ++ni) {
                const int cg = col0 + wc + ni * 16 + l15;
                const float bv = bias[cg];
#pragma unroll
                for (int j = 0; j < 4; ++j) {
                    const int rg = row0 + wr + mi * 16 + lg * 4 + j;
                    const float val = (acc[mi][ni][j] + bv) * scl;
                    const int bb = rg >> 10, ss = rg & 1023;
                    const int hh2 = cg >> 6, dd = cg & 63;
                    O[((size_t)(bb * Hh + hh2) * Ss + ss) * DKk + dd] = (__bf16)val;
                }
            }
        }
    }
}

// ---- output projection: bf16 A [M][768] x bf16 Wo -> fp32 [M][768] + bias ----
__global__ __launch_bounds__(256) void o_gemm(const __bf16* __restrict__ A, const __bf16* __restrict__ W,
                                              const float* __restrict__ bias, float* __restrict__ Out) {
    __shared__ __attribute__((aligned(16))) char smem[32768];
    const int t = (int)threadIdx.x;
    const int lane = t & 63, w = t >> 6;
    const int l15 = lane & 15, lg = lane >> 4;
    const int row0 = (int)blockIdx.x * 128, col0 = (int)blockIdx.y * 128;
    const int wr = (w >> 1) * 64, wc = (w & 1) * 64;

    f32x4 acc[4][4] = {};
    gemm_core<false>((const void*)A, W, smem, row0, col0, t, acc);

#pragma unroll
    for (int mi = 0; mi < 4; ++mi) {
#pragma unroll
        for (int ni = 0; ni < 4; ++ni) {
            const int cg = col0 + wc + ni * 16 + l15;
            const float bv = bias[cg];
#pragma unroll
            for (int j = 0; j < 4; ++j) {
                const int rg = row0 + wr + mi * 16 + lg * 4 + j;
                Out[(size_t)rg * Dd + cg] = acc[mi][ni][j] + bv;
            }
        }
    }
}

// ---- Flash attention v8 (unchanged): QBLK=64, NO-MAX base-2 softmax,
// T14 async-STAGE split + T5 setprio. 1536 blocks, 96-bijective XCD grouping. ----
__global__ __launch_bounds__(256) void attn_k(const __bf16* __restrict__ q,
                                              const __bf16* __restrict__ k,
                                              const __bf16* __restrict__ vt,
                                              __bf16* __restrict__ o) {
    __shared__ __attribute__((aligned(16))) __bf16 Ks[64][72];   // [key][d]
    __shared__ __attribute__((aligned(16))) __bf16 Vs[64][72];   // [d][key]
    __shared__ __attribute__((aligned(16))) __bf16 plds[4][16][72];
    const int t = (int)threadIdx.x;
    const int lane = t & 63, w = t >> 6;
    const int l15 = lane & 15, lg = lane >> 4;
    const int blk = (int)blockIdx.x;
    const int bh = blk % 96, qt = blk / 96;   // 96 % 8 == 0: bijective XCD grouping
    const size_t bhb = (size_t)bh * Ss;
    const __bf16* qp = q + bhb * DKk;
    const __bf16* kp = k + bhb * DKk;
    const __bf16* vtp = vt + bhb * DKk;  // V^T: [64 d][1024 s]
    const int qbase = qt * 64 + w * 16;
    const int srow = t >> 2, sc = (t & 3) * 16;  // staging: row, 16-elem chunk base

    // Q as MFMA B-operand: col = l15 = q-row, k = ks*32 + lg*8
    bfrag bq[2];
#pragma unroll
    for (int ks = 0; ks < 2; ++ks)
        bq[ks] = *reinterpret_cast<const bfrag*>(qp + (size_t)(qbase + l15) * DKk + ks * 32 + lg * 8);

    float lrow = 0.f;            // per-lane denom for q = l15 (replicated over lg)
    f32x4 oacc[4] = {};

    {   // prologue: stage tile 0
        bfrag k0a = *reinterpret_cast<const bfrag*>(kp + (size_t)srow * DKk + sc);
        bfrag k0b = *reinterpret_cast<const bfrag*>(kp + (size_t)srow * DKk + sc + 8);
        bfrag v0a = *reinterpret_cast<const bfrag*>(vtp + (size_t)srow * Ss + sc);
        bfrag v0b = *reinterpret_cast<const bfrag*>(vtp + (size_t)srow * Ss + sc + 8);
        *reinterpret_cast<bfrag*>(&Ks[srow][sc]) = k0a;
        *reinterpret_cast<bfrag*>(&Ks[srow][sc + 8]) = k0b;
        *reinterpret_cast<bfrag*>(&Vs[srow][sc]) = v0a;
        *reinterpret_cast<bfrag*>(&Vs[srow][sc + 8]) = v0b;
    }
    __syncthreads();

    for (int kt = 0; kt < 16; ++kt) {
        // T14: issue next tile's global loads BEFORE compute; write after barrier
        bfrag kna, knb, vna, vnb;
        if (kt < 15) {
            const int kb1 = (kt + 1) * 64;
            kna = *reinterpret_cast<const bfrag*>(kp + (size_t)(kb1 + srow) * DKk + sc);
            knb = *reinterpret_cast<const bfrag*>(kp + (size_t)(kb1 + srow) * DKk + sc + 8);
            vna = *reinterpret_cast<const bfrag*>(vtp + (size_t)srow * Ss + kb1 + sc);
            vnb = *reinterpret_cast<const bfrag*>(vtp + (size_t)srow * Ss + kb1 + sc + 8);
        }

        // QK^T swapped: A = K rows (key), B = Q cols (q). sacc[n][j]: key = n*16+lg*4+j, q = l15
        f32x4 sacc[4] = {};
        __builtin_amdgcn_s_setprio(1);
#pragma unroll
        for (int n = 0; n < 4; ++n) {
#pragma unroll
            for (int ks = 0; ks < 2; ++ks) {
                const bfrag ak = *reinterpret_cast<const bfrag*>(&Ks[n * 16 + l15][ks * 32 + lg * 8]);
                sacc[n] = __builtin_amdgcn_mfma_f32_16x16x32_bf16(ak, bq[ks], sacc[n], 0, 0, 0);
            }
        }
        __builtin_amdgcn_s_setprio(0);

        // no-max softmax: p = exp2(s) (Q pre-scaled by 0.125*log2e), accumulate denom
        float p[4][4];
        float rs = 0.f;
#pragma unroll
        for (int n = 0; n < 4; ++n)
#pragma unroll
            for (int j = 0; j < 4; ++j) {
                const float pe = EXP2(sacc[n][j]);
                p[n][j] = pe;
                rs += pe;
            }
        rs += __shfl_xor(rs, 16);
        rs += __shfl_xor(rs, 32);
        lrow += rs;

        // P -> wave-private LDS, packed b64: row = q = l15, keys n*16+lg*4+{0..3}
#pragma unroll
        for (int n = 0; n < 4; ++n) {
            bf16x4 pk;
#pragma unroll
            for (int j = 0; j < 4; ++j) pk[j] = (__bf16)p[n][j];
            *reinterpret_cast<bf16x4*>(&plds[w][l15][n * 16 + lg * 4]) = pk;
        }

        // PV: A = P (row = q = l15, k = key), B = V^T tile in LDS (col = d = l15)
        __builtin_amdgcn_s_setprio(1);
#pragma unroll
        for (int ks = 0; ks < 2; ++ks) {
            const bfrag ap = *reinterpret_cast<const bfrag*>(&plds[w][l15][ks * 32 + lg * 8]);
#pragma unroll
            for (int dt = 0; dt < 4; ++dt) {
                const bfrag bv = *reinterpret_cast<const bfrag*>(&Vs[dt * 16 + l15][ks * 32 + lg * 8]);
                oacc[dt] = __builtin_amdgcn_mfma_f32_16x16x32_bf16(ap, bv, oacc[dt], 0, 0, 0);
            }
        }
        __builtin_amdgcn_s_setprio(0);

        __syncthreads();  // all waves done reading Ks/Vs
        if (kt < 15) {
            *reinterpret_cast<bfrag*>(&Ks[srow][sc]) = kna;
            *reinterpret_cast<bfrag*>(&Ks[srow][sc + 8]) = knb;
            *reinterpret_cast<bfrag*>(&Vs[srow][sc]) = vna;
            *reinterpret_cast<bfrag*>(&Vs[srow][sc + 8]) = vnb;
        }
        __syncthreads();  // writes visible
    }

    // epilogue: divide by l for q = lg*4+j (held by lane lg*4+j), write [B,S,D]
    float linv[4];
#pragma unroll
    for (int j = 0; j < 4; ++j) linv[j] = 1.0f / __shfl(lrow, lg * 4 + j);
    const int bb = bh / Hh, hh = bh % Hh;
#pragma unroll
    for (int dt = 0; dt < 4; ++dt)
#pragma unroll
        for (int j = 0; j < 4; ++j) {
            const int qrow = qbase + lg * 4 + j;
            o[((size_t)(bb * Ss + qrow)) * Dd + hh * DKk + dt * 16 + l15] =
                (__bf16)(oacc[dt][j] * linv[j]);
        }
}

extern "C" void kernel_launch(void* const* d_in, const int* in_sizes, int n_in,
                              void* d_out, int out_size, void* d_ws, size_t ws_size,
                              hipStream_t stream) {
    (void)in_sizes; (void)n_in; (void)out_size; (void)ws_size;
    // dict order: key, query, value, Wk, bk, Wq, bq, Wv, bv, Wo, bo
    const float* key   = (const float*)d_in[0];
    const float* query = (const float*)d_in[1];
    const float* value = (const float*)d_in[2];
    const float* Wk = (const float*)d_in[3];
    const float* bk = (const float*)d_in[4];
    const float* Wq = (const float*)d_in[5];
    const float* bq = (const float*)d_in[6];
    const float* Wv = (const float*)d_in[7];
    const float* bvp = (const float*)d_in[8];
    const float* Wo = (const float*)d_in[9];
    const float* bo = (const float*)d_in[10];

    const size_t NA = (size_t)Mm * Dd;   // 6291456 activation elems
    const size_t NW = (size_t)Dd * Dd;   // 589824 weight elems
    __bf16* p = (__bf16*)d_ws;
    __bf16* wqb = p;            p += NW;
    __bf16* wkb = p;            p += NW;
    __bf16* wvb = p;            p += NW;
    __bf16* wob = p;            p += NW;
    __bf16* qws = p;            p += NA;   // Q proj (scaled by 0.125*log2e)
    __bf16* kws = p;            p += NA;   // K proj
    __bf16* vtws = p;           p += NA;   // V^T proj
    __bf16* aws = p;            p += NA;   // attn out

    dim3 blk(256);
    cvtw_k<<<dim3(1152), blk, 0, stream>>>(Wq, Wk, Wv, Wo, wqb, wkb, wvb, wob);
    qkv_gemm<<<dim3(Mm / 128, Dd / 128, 3), blk, 0, stream>>>(query, key, value,
                                                              wqb, wkb, wvb,
                                                              bq, bk, bvp,
                                                              qws, kws, vtws);
    attn_k<<<dim3(Ss / 64 * Hh * Bb), blk, 0, stream>>>(qws, kws, vtws, aws);
    o_gemm<<<dim3(Mm / 128, Dd / 128), blk, 0, stream>>>(aws, wob, bo, (float*)d_out);
}